// Round 1
// baseline (435.501 us; speedup 1.0000x reference)
//
#include <hip/hip_runtime.h>
#include <math.h>

#define VIF_EPS       1e-10f
#define SIGMA_NSQ     2.0f
#define SIGMA_MAX_INV (4.0f / (255.0f * 255.0f))
#define GAIN_LIMIT    100.0f

#define TW 32
#define TH 8

// jnp.pad mode='reflect' (no edge duplication). Overshoot < dim, single reflection suffices.
__device__ __forceinline__ int reflect_idx(int i, int n) {
    i = (i < 0) ? -i : i;
    i = (i >= n) ? (2 * n - 2 - i) : i;
    return i;
}

// Reference: sigma=N/5; g=exp(-x^2/(2 sigma^2)); win=outer(g,g)/sum -> separable gn = g/sum(g).
template <int N>
__device__ __forceinline__ void compute_weights(float* wts) {
    if (threadIdx.x == 0) {
        const float sigma = (float)N / 5.0f;
        const float denom = 2.0f * sigma * sigma;
        float s = 0.0f;
        for (int i = 0; i < N; ++i) {
            float x = (float)i - (float)(N - 1) * 0.5f;
            float g = expf(-(x * x) / denom);
            wts[i] = g;
            s += g;
        }
        for (int i = 0; i < N; ++i) wts[i] = wts[i] / s;
    }
}

// Per-tile separable 5-channel Gaussian stats + VIF per-pixel math + block reduction.
// Writes deterministic per-block partial sums (num, den) as double2.
template <int N>
__global__ __launch_bounds__(256) void stats_kernel(
    const float* __restrict__ refp, const float* __restrict__ distp,
    int h, int w, float shift, double2* __restrict__ partial) {
    constexpr int P  = (N - 1) / 2;
    constexpr int PW = TW + 2 * P;
    constexpr int PH = TH + 2 * P;

    __shared__ float wts[N];
    __shared__ float lref[PH][PW];
    __shared__ float ldist[PH][PW];
    __shared__ float hc[5][PH][TW];
    __shared__ float rsum[8];

    const int tid = threadIdx.x;
    const int b   = blockIdx.z;
    const int x0  = blockIdx.x * TW;
    const int y0  = blockIdx.y * TH;

    compute_weights<N>(wts);

    const float* rb = refp  + (size_t)b * h * w;
    const float* db = distp + (size_t)b * h * w;

    // Stage padded ref/dist patch (reflect indexing), applying the -128 shift for scale 0.
    for (int idx = tid; idx < PH * PW; idx += 256) {
        int py = idx / PW;
        int px = idx - py * PW;
        int gy = reflect_idx(y0 + py - P, h);
        int gx = reflect_idx(x0 + px - P, w);
        lref[py][px]  = rb[(size_t)gy * w + gx] - shift;
        ldist[py][px] = db[(size_t)gy * w + gx] - shift;
    }
    __syncthreads();

    // Horizontal 1D conv of the 5 product channels.
    for (int idx = tid; idx < PH * TW; idx += 256) {
        int py = idx >> 5;   // TW == 32
        int px = idx & 31;
        float a1 = 0.f, a2 = 0.f, a11 = 0.f, a22 = 0.f, a12 = 0.f;
#pragma unroll
        for (int j = 0; j < N; ++j) {
            float wt = wts[j];
            float r  = lref[py][px + j];
            float d  = ldist[py][px + j];
            a1  += wt * r;
            a2  += wt * d;
            a11 += wt * (r * r);
            a22 += wt * (d * d);
            a12 += wt * (r * d);
        }
        hc[0][py][px] = a1;
        hc[1][py][px] = a2;
        hc[2][py][px] = a11;
        hc[3][py][px] = a22;
        hc[4][py][px] = a12;
    }
    __syncthreads();

    // Vertical 1D conv + VIF per-pixel math. One pixel per thread (32x8 tile).
    const int tx = tid & 31;
    const int ty = tid >> 5;
    float num_v = 0.f, den_v = 0.f;
    const int gx = x0 + tx;
    const int gy = y0 + ty;
    if (gx < w && gy < h) {
        float mu1 = 0.f, mu2 = 0.f, m11 = 0.f, m22 = 0.f, m12 = 0.f;
#pragma unroll
        for (int i = 0; i < N; ++i) {
            float wt = wts[i];
            mu1 += wt * hc[0][ty + i][tx];
            mu2 += wt * hc[1][ty + i][tx];
            m11 += wt * hc[2][ty + i][tx];
            m22 += wt * hc[3][ty + i][tx];
            m12 += wt * hc[4][ty + i][tx];
        }
        float s1  = fmaxf(0.f, m11 - mu1 * mu1);
        float s2  = fmaxf(0.f, m22 - mu2 * mu2);
        float s12 = m12 - mu1 * mu2;

        float g  = s12 / (s1 + VIF_EPS);
        float sv = s2 - g * s12;
        if (s1 < VIF_EPS) { g = 0.f; sv = s2; s1 = 0.f; }
        if (s2 < VIF_EPS) { g = 0.f; sv = 0.f; }
        if (g  < 0.f)     { sv = s2; g = 0.f; }   // sv where(g<0) then relu(g)
        if (sv <= VIF_EPS) sv = VIF_EPS;
        g = fminf(g, GAIN_LIMIT);

        float num_ar = __log2f(1.f + g * g * s1 / (sv + SIGMA_NSQ));
        float den_ar = __log2f(1.f + s1 / SIGMA_NSQ);
        if (s12 < 0.f) num_ar = 0.f;
        if (s1 < SIGMA_NSQ) { num_ar = 1.f - s2 * SIGMA_MAX_INV; den_ar = 1.f; }
        num_v = num_ar;
        den_v = den_ar;
    }

    // Block reduction: wave shuffle then cross-wave via LDS.
#pragma unroll
    for (int off = 32; off > 0; off >>= 1) {
        num_v += __shfl_down(num_v, off);
        den_v += __shfl_down(den_v, off);
    }
    const int wid = tid >> 6, lane = tid & 63;
    if (lane == 0) { rsum[wid] = num_v; rsum[4 + wid] = den_v; }
    __syncthreads();
    if (tid == 0) {
        float ns = rsum[0] + rsum[1] + rsum[2] + rsum[3];
        float ds = rsum[4] + rsum[5] + rsum[6] + rsum[7];
        size_t pidx = ((size_t)b * gridDim.y + blockIdx.y) * gridDim.x + blockIdx.x;
        partial[pidx] = make_double2((double)ns, (double)ds);
    }
}

// Stride-2 separable Gaussian downsample with reflect padding. One output pixel/thread.
template <int N>
__global__ __launch_bounds__(256) void down_kernel(
    const float* __restrict__ rin, const float* __restrict__ din,
    float* __restrict__ rout, float* __restrict__ dout,
    int h, int w, int h2, int w2, float shift) {
    constexpr int P = (N - 1) / 2;
    __shared__ float wts[N];
    compute_weights<N>(wts);
    __syncthreads();

    const int b   = blockIdx.z;
    const int img = blockIdx.y;  // 0 = ref, 1 = dist
    const float* in  = (img ? din : rin) + (size_t)b * h * w;
    float*       out = (img ? dout : rout) + (size_t)b * h2 * w2;

    int idx = blockIdx.x * 256 + threadIdx.x;
    if (idx >= h2 * w2) return;
    int y = idx / w2;
    int x = idx - y * w2;

    float acc = 0.f;
#pragma unroll
    for (int i = 0; i < N; ++i) {
        int gy = reflect_idx(2 * y + i - P, h);
        float row = 0.f;
#pragma unroll
        for (int j = 0; j < N; ++j) {
            int gx = reflect_idx(2 * x + j - P, w);
            row += wts[j] * (in[(size_t)gy * w + gx] - shift);
        }
        acc += wts[i] * row;
    }
    out[idx] = acc;
}

// 16 blocks: one per (batch, scale). Sums double2 partials, writes num/den to out.
__global__ __launch_bounds__(256) void reduce_kernel(
    const double2* __restrict__ part, float* __restrict__ out,
    int4 bases, int4 counts) {
    __shared__ double sn[4], sd[4];
    const int s = blockIdx.x & 3;
    const int b = blockIdx.x >> 2;
    const int base = (&bases.x)[s];
    const int cnt  = (&counts.x)[s];
    const double2* p = part + base + (size_t)b * cnt;

    double ns = 0.0, ds = 0.0;
    for (int i = threadIdx.x; i < cnt; i += 256) {
        double2 v = p[i];
        ns += v.x;
        ds += v.y;
    }
#pragma unroll
    for (int off = 32; off > 0; off >>= 1) {
        ns += __shfl_down(ns, off);
        ds += __shfl_down(ds, off);
    }
    const int wid = threadIdx.x >> 6, lane = threadIdx.x & 63;
    if (lane == 0) { sn[wid] = ns; sd[wid] = ds; }
    __syncthreads();
    if (threadIdx.x == 0) {
        double N = sn[0] + sn[1] + sn[2] + sn[3];
        double D = sd[0] + sd[1] + sd[2] + sd[3];
        out[b * 4 + s] = (float)(N / D);
    }
}

extern "C" void kernel_launch(void* const* d_in, const int* in_sizes, int n_in,
                              void* d_out, int out_size, void* d_ws, size_t ws_size,
                              hipStream_t stream) {
    const float* ref  = (const float*)d_in[0];
    const float* dist = (const float*)d_in[1];
    float* out = (float*)d_out;

    const int B = 4;
    const int H0 = 1080, W0 = 1920;
    const int H1 = 540,  W1 = 960;
    const int H2 = 270,  W2 = 480;
    const int H3 = 135,  W3 = 240;

    // ws layout (poisoned each call; every byte we read is written first this call)
    char*  ws  = (char*)d_ws;
    size_t off = 0;
    auto alloc = [&](size_t bytes) -> void* {
        void* p = ws + off;
        off += (bytes + 255) & ~(size_t)255;
        return p;
    };
    float* ref1  = (float*)alloc((size_t)B * H1 * W1 * 4);
    float* dist1 = (float*)alloc((size_t)B * H1 * W1 * 4);
    float* ref2  = (float*)alloc((size_t)B * H2 * W2 * 4);
    float* dist2 = (float*)alloc((size_t)B * H2 * W2 * 4);
    float* ref3  = (float*)alloc((size_t)B * H3 * W3 * 4);
    float* dist3 = (float*)alloc((size_t)B * H3 * W3 * 4);

    const int tx0 = (W0 + TW - 1) / TW, ty0 = (H0 + TH - 1) / TH;  // 60 x 135
    const int tx1 = (W1 + TW - 1) / TW, ty1 = (H1 + TH - 1) / TH;  // 30 x 68
    const int tx2 = (W2 + TW - 1) / TW, ty2 = (H2 + TH - 1) / TH;  // 15 x 34
    const int tx3 = (W3 + TW - 1) / TW, ty3 = (H3 + TH - 1) / TH;  // 8 x 17
    const int n0 = tx0 * ty0, n1 = tx1 * ty1, n2 = tx2 * ty2, n3 = tx3 * ty3;

    double2* part = (double2*)alloc((size_t)B * (n0 + n1 + n2 + n3) * sizeof(double2));
    double2* p0 = part;
    double2* p1 = p0 + (size_t)B * n0;
    double2* p2 = p1 + (size_t)B * n1;
    double2* p3 = p2 + (size_t)B * n2;

    dim3 blk(256);

    // Scale 0: stats on original (shift 128)
    stats_kernel<17><<<dim3(tx0, ty0, B), blk, 0, stream>>>(ref, dist, H0, W0, 128.0f, p0);

    // Scale 1
    down_kernel<9><<<dim3((H1 * W1 + 255) / 256, 2, B), blk, 0, stream>>>(
        ref, dist, ref1, dist1, H0, W0, H1, W1, 128.0f);
    stats_kernel<9><<<dim3(tx1, ty1, B), blk, 0, stream>>>(ref1, dist1, H1, W1, 0.0f, p1);

    // Scale 2
    down_kernel<5><<<dim3((H2 * W2 + 255) / 256, 2, B), blk, 0, stream>>>(
        ref1, dist1, ref2, dist2, H1, W1, H2, W2, 0.0f);
    stats_kernel<5><<<dim3(tx2, ty2, B), blk, 0, stream>>>(ref2, dist2, H2, W2, 0.0f, p2);

    // Scale 3
    down_kernel<3><<<dim3((H3 * W3 + 255) / 256, 2, B), blk, 0, stream>>>(
        ref2, dist2, ref3, dist3, H2, W2, H3, W3, 0.0f);
    stats_kernel<3><<<dim3(tx3, ty3, B), blk, 0, stream>>>(ref3, dist3, H3, W3, 0.0f, p3);

    // Final: num/den per (b, scale)
    reduce_kernel<<<16, 256, 0, stream>>>(
        part, out,
        make_int4(0, B * n0, B * (n0 + n1), B * (n0 + n1 + n2)),
        make_int4(n0, n1, n2, n3));
}

// Round 2
// 349.611 us; speedup vs baseline: 1.2457x; 1.2457x over previous
//
#include <hip/hip_runtime.h>
#include <math.h>

#define VIF_EPS       1e-10f
#define SIGMA_NSQ     2.0f
#define SIGMA_MAX_INV (4.0f / (255.0f * 255.0f))
#define GAIN_LIMIT    100.0f

// jnp.pad mode='reflect' (no edge duplication). Overshoot < dim, single reflection suffices.
__device__ __forceinline__ int reflect_idx(int i, int n) {
    i = (i < 0) ? -i : i;
    i = (i >= n) ? (2 * n - 2 - i) : i;
    return i;
}

// Reference: sigma=N/5; g=exp(-x^2/(2 sigma^2)); win=outer(g,g)/sum -> separable gn = g/sum(g).
template <int N>
__device__ __forceinline__ void compute_weights(float* wts) {
    if (threadIdx.x == 0) {
        const float sigma = (float)N / 5.0f;
        const float denom = 2.0f * sigma * sigma;
        float s = 0.0f;
        for (int i = 0; i < N; ++i) {
            float x = (float)i - (float)(N - 1) * 0.5f;
            float g = expf(-(x * x) / denom);
            wts[i] = g;
            s += g;
        }
        for (int i = 0; i < N; ++i) wts[i] = wts[i] / s;
    }
}

// Separable 5-channel Gaussian stats + VIF per-pixel math + block reduction.
// 32x32 output tile, 256 threads (4 outputs/thread). Product channels staged once.
// Horizontal pass: 4 consecutive x per thread from one float4-loaded register window;
// results round-trip via registers so the hc buffer overlays the staging buffer.
template <int N>
__global__ __launch_bounds__(256) void stats_kernel(
    const float* __restrict__ refp, const float* __restrict__ distp,
    int h, int w, float shift, double2* __restrict__ partial) {
    constexpr int P   = (N - 1) / 2;
    constexpr int TS  = 32;
    constexpr int PH  = TS + 2 * P;
    constexpr int PW  = TS + 2 * P;
    constexpr int PWP = ((PW + 3) / 4) * 4;   // float4-padded row
    constexpr int F4  = (N + 6) / 4;          // float4 loads per h window (>= N+3 floats)
    constexpr int NG  = PH * (TS / 4);        // horizontal groups of 4
    constexpr int KG  = (NG + 255) / 256;

    __shared__ float wts[N];
    __shared__ __align__(16) float chbuf[5 * PH * PWP];
    __shared__ float rsum[8];

    const int tid = threadIdx.x;
    const int b   = blockIdx.z;
    const int x0  = blockIdx.x * TS;
    const int y0  = blockIdx.y * TS;

    compute_weights<N>(wts);

    const float* rb = refp  + (size_t)b * h * w;
    const float* db = distp + (size_t)b * h * w;

    // Stage 5 channels (r, d, rr, dd, rd), reflect-padded; products computed ONCE here.
    for (int idx = tid; idx < PH * PWP; idx += 256) {
        int py = idx / PWP;
        int px = idx - py * PWP;
        int gy = reflect_idx(y0 + py - P, h);
        int gx = reflect_idx(x0 + px - P, w);
        float r = rb[(size_t)gy * w + gx] - shift;
        float d = db[(size_t)gy * w + gx] - shift;
        int base = py * PWP + px;
        chbuf[0 * PH * PWP + base] = r;
        chbuf[1 * PH * PWP + base] = d;
        chbuf[2 * PH * PWP + base] = r * r;
        chbuf[3 * PH * PWP + base] = d * d;
        chbuf[4 * PH * PWP + base] = r * d;
    }
    __syncthreads();

    // Horizontal pass -> registers.
    float hreg[KG][5][4];
#pragma unroll
    for (int k = 0; k < KG; ++k) {
        int g = tid + k * 256;
        if (g < NG) {
            int py = g >> 3;
            int xg = (g & 7) * 4;
#pragma unroll
            for (int c = 0; c < 5; ++c) {
                float win[F4 * 4];
                const float4* src4 = (const float4*)&chbuf[(c * PH + py) * PWP + xg];
#pragma unroll
                for (int f = 0; f < F4; ++f) {
                    float4 v = src4[f];
                    win[4 * f + 0] = v.x; win[4 * f + 1] = v.y;
                    win[4 * f + 2] = v.z; win[4 * f + 3] = v.w;
                }
#pragma unroll
                for (int q = 0; q < 4; ++q) {
                    float a = 0.f;
#pragma unroll
                    for (int j = 0; j < N; ++j) a += wts[j] * win[q + j];
                    hreg[k][c][q] = a;
                }
            }
        }
    }
    __syncthreads();

    // Write hc overlaid on chbuf: layout [5][PH][32].
#pragma unroll
    for (int k = 0; k < KG; ++k) {
        int g = tid + k * 256;
        if (g < NG) {
            int py = g >> 3;
            int xg = (g & 7) * 4;
#pragma unroll
            for (int c = 0; c < 5; ++c) {
                float4* dst = (float4*)&chbuf[(c * PH + py) * TS + xg];
                *dst = make_float4(hreg[k][c][0], hreg[k][c][1], hreg[k][c][2], hreg[k][c][3]);
            }
        }
    }
    __syncthreads();

    // Vertical pass: each thread = 1 column x 4 consecutive rows, register window.
    const int tx  = tid & 31;
    const int ty0 = (tid >> 5) * 4;
    float mu[5][4];
#pragma unroll
    for (int c = 0; c < 5; ++c) {
        float win[N + 3];
#pragma unroll
        for (int r = 0; r < N + 3; ++r)
            win[r] = chbuf[(c * PH + ty0 + r) * TS + tx];
#pragma unroll
        for (int q = 0; q < 4; ++q) {
            float a = 0.f;
#pragma unroll
            for (int j = 0; j < N; ++j) a += wts[j] * win[q + j];
            mu[c][q] = a;
        }
    }

    float num_v = 0.f, den_v = 0.f;
#pragma unroll
    for (int q = 0; q < 4; ++q) {
        int gx = x0 + tx;
        int gy = y0 + ty0 + q;
        if (gx < w && gy < h) {
            float mu1 = mu[0][q], mu2 = mu[1][q];
            float s1  = fmaxf(0.f, mu[2][q] - mu1 * mu1);
            float s2  = fmaxf(0.f, mu[3][q] - mu2 * mu2);
            float s12 = mu[4][q] - mu1 * mu2;

            float g  = s12 / (s1 + VIF_EPS);
            float sv = s2 - g * s12;
            if (s1 < VIF_EPS) { g = 0.f; sv = s2; s1 = 0.f; }
            if (s2 < VIF_EPS) { g = 0.f; sv = 0.f; }
            if (g  < 0.f)     { sv = s2; g = 0.f; }
            if (sv <= VIF_EPS) sv = VIF_EPS;
            g = fminf(g, GAIN_LIMIT);

            float num_ar = __log2f(1.f + g * g * s1 / (sv + SIGMA_NSQ));
            float den_ar = __log2f(1.f + s1 / SIGMA_NSQ);
            if (s12 < 0.f) num_ar = 0.f;
            if (s1 < SIGMA_NSQ) { num_ar = 1.f - s2 * SIGMA_MAX_INV; den_ar = 1.f; }
            num_v += num_ar;
            den_v += den_ar;
        }
    }

    // Block reduction: wave shuffle then cross-wave via LDS.
#pragma unroll
    for (int off = 32; off > 0; off >>= 1) {
        num_v += __shfl_down(num_v, off);
        den_v += __shfl_down(den_v, off);
    }
    const int wid = tid >> 6, lane = tid & 63;
    if (lane == 0) { rsum[wid] = num_v; rsum[4 + wid] = den_v; }
    __syncthreads();
    if (tid == 0) {
        float ns = rsum[0] + rsum[1] + rsum[2] + rsum[3];
        float ds = rsum[4] + rsum[5] + rsum[6] + rsum[7];
        size_t pidx = ((size_t)b * gridDim.y + blockIdx.y) * gridDim.x + blockIdx.x;
        partial[pidx] = make_double2((double)ns, (double)ds);
    }
}

// Separable stride-2 Gaussian downsample, LDS-tiled, both images per block.
// 32x8 output tile. Horizontal pass decimates x with float4 register windows.
template <int N>
__global__ __launch_bounds__(256) void down_kernel(
    const float* __restrict__ rin, const float* __restrict__ din,
    float* __restrict__ rout, float* __restrict__ dout,
    int h, int w, int h2, int w2, float shift) {
    constexpr int P   = (N - 1) / 2;
    constexpr int TOX = 32, TOY = 8;
    constexpr int IH  = 2 * (TOY - 1) + N;    // input rows needed
    constexpr int IW  = 2 * (TOX - 1) + N;    // input cols needed
    constexpr int IWP = ((IW + 3) / 4) * 4;
    constexpr int F4  = (N + 10) / 4;         // float4 loads per decimated h window
    constexpr int NG  = 2 * IH * (TOX / 4);

    __shared__ float wts[N];
    __shared__ __align__(16) float lin[2 * IH * IWP];
    __shared__ float hd[2][IH][TOX];

    compute_weights<N>(wts);

    const int tid = threadIdx.x;
    const int b   = blockIdx.z;
    const int x0  = blockIdx.x * TOX;
    const int y0  = blockIdx.y * TOY;

    const float* src0 = rin + (size_t)b * h * w;
    const float* src1 = din + (size_t)b * h * w;

    // Stage both images, reflect-padded, shifted.
    for (int idx = tid; idx < 2 * IH * IWP; idx += 256) {
        int img = idx / (IH * IWP);
        int rem = idx - img * IH * IWP;
        int r   = rem / IWP;
        int cx  = rem - r * IWP;
        int gy  = reflect_idx(2 * y0 - P + r, h);
        int gx  = reflect_idx(2 * x0 - P + cx, w);
        const float* src = img ? src1 : src0;
        lin[idx] = src[(size_t)gy * w + gx] - shift;
    }
    __syncthreads();

    // Horizontal decimating pass: 4 consecutive x-outputs per group.
    for (int g = tid; g < NG; g += 256) {
        int img = g / (IH * 8);
        int rem = g - img * IH * 8;
        int r   = rem >> 3;
        int xg  = (rem & 7) * 4;
        float win[F4 * 4];
        const float4* src4 = (const float4*)&lin[(img * IH + r) * IWP + 2 * xg];
#pragma unroll
        for (int f = 0; f < F4; ++f) {
            float4 v = src4[f];
            win[4 * f + 0] = v.x; win[4 * f + 1] = v.y;
            win[4 * f + 2] = v.z; win[4 * f + 3] = v.w;
        }
#pragma unroll
        for (int q = 0; q < 4; ++q) {
            float a = 0.f;
#pragma unroll
            for (int j = 0; j < N; ++j) a += wts[j] * win[2 * q + j];
            hd[img][r][xg + q] = a;
        }
    }
    __syncthreads();

    // Vertical decimating pass: 2 outputs per thread.
    const int img = tid >> 7;
    const int rem = tid & 127;
    const int tx  = rem & 31;
    const int yg  = (rem >> 5) * 2;
    float* outp = (img ? dout : rout) + (size_t)b * h2 * w2;
#pragma unroll
    for (int q = 0; q < 2; ++q) {
        int yo = yg + q;
        int gy = y0 + yo, gx = x0 + tx;
        if (gy < h2 && gx < w2) {
            float a = 0.f;
#pragma unroll
            for (int j = 0; j < N; ++j) a += wts[j] * hd[img][2 * yo + j][tx];
            outp[(size_t)gy * w2 + gx] = a;
        }
    }
}

// 16 blocks: one per (batch, scale). Sums double2 partials, writes num/den to out.
__global__ __launch_bounds__(256) void reduce_kernel(
    const double2* __restrict__ part, float* __restrict__ out,
    int4 bases, int4 counts) {
    __shared__ double sn[4], sd[4];
    const int s = blockIdx.x & 3;
    const int b = blockIdx.x >> 2;
    const int base = (&bases.x)[s];
    const int cnt  = (&counts.x)[s];
    const double2* p = part + base + (size_t)b * cnt;

    double ns = 0.0, ds = 0.0;
    for (int i = threadIdx.x; i < cnt; i += 256) {
        double2 v = p[i];
        ns += v.x;
        ds += v.y;
    }
#pragma unroll
    for (int off = 32; off > 0; off >>= 1) {
        ns += __shfl_down(ns, off);
        ds += __shfl_down(ds, off);
    }
    const int wid = threadIdx.x >> 6, lane = threadIdx.x & 63;
    if (lane == 0) { sn[wid] = ns; sd[wid] = ds; }
    __syncthreads();
    if (threadIdx.x == 0) {
        double Nv = sn[0] + sn[1] + sn[2] + sn[3];
        double Dv = sd[0] + sd[1] + sd[2] + sd[3];
        out[b * 4 + s] = (float)(Nv / Dv);
    }
}

extern "C" void kernel_launch(void* const* d_in, const int* in_sizes, int n_in,
                              void* d_out, int out_size, void* d_ws, size_t ws_size,
                              hipStream_t stream) {
    const float* ref  = (const float*)d_in[0];
    const float* dist = (const float*)d_in[1];
    float* out = (float*)d_out;

    const int B = 4;
    const int H0 = 1080, W0 = 1920;
    const int H1 = 540,  W1 = 960;
    const int H2 = 270,  W2 = 480;
    const int H3 = 135,  W3 = 240;

    char*  ws  = (char*)d_ws;
    size_t off = 0;
    auto alloc = [&](size_t bytes) -> void* {
        void* p = ws + off;
        off += (bytes + 255) & ~(size_t)255;
        return p;
    };
    float* ref1  = (float*)alloc((size_t)B * H1 * W1 * 4);
    float* dist1 = (float*)alloc((size_t)B * H1 * W1 * 4);
    float* ref2  = (float*)alloc((size_t)B * H2 * W2 * 4);
    float* dist2 = (float*)alloc((size_t)B * H2 * W2 * 4);
    float* ref3  = (float*)alloc((size_t)B * H3 * W3 * 4);
    float* dist3 = (float*)alloc((size_t)B * H3 * W3 * 4);

    const int tx0 = (W0 + 31) / 32, ty0 = (H0 + 31) / 32;  // 60 x 34
    const int tx1 = (W1 + 31) / 32, ty1 = (H1 + 31) / 32;  // 30 x 17
    const int tx2 = (W2 + 31) / 32, ty2 = (H2 + 31) / 32;  // 15 x 9
    const int tx3 = (W3 + 31) / 32, ty3 = (H3 + 31) / 32;  // 8 x 5
    const int n0 = tx0 * ty0, n1 = tx1 * ty1, n2 = tx2 * ty2, n3 = tx3 * ty3;

    double2* part = (double2*)alloc((size_t)B * (n0 + n1 + n2 + n3) * sizeof(double2));
    double2* p0 = part;
    double2* p1 = p0 + (size_t)B * n0;
    double2* p2 = p1 + (size_t)B * n1;
    double2* p3 = p2 + (size_t)B * n2;

    dim3 blk(256);

    // Scale 0: stats on original (shift 128)
    stats_kernel<17><<<dim3(tx0, ty0, B), blk, 0, stream>>>(ref, dist, H0, W0, 128.0f, p0);

    // Scale 1
    down_kernel<9><<<dim3((W1 + 31) / 32, (H1 + 7) / 8, B), blk, 0, stream>>>(
        ref, dist, ref1, dist1, H0, W0, H1, W1, 128.0f);
    stats_kernel<9><<<dim3(tx1, ty1, B), blk, 0, stream>>>(ref1, dist1, H1, W1, 0.0f, p1);

    // Scale 2
    down_kernel<5><<<dim3((W2 + 31) / 32, (H2 + 7) / 8, B), blk, 0, stream>>>(
        ref1, dist1, ref2, dist2, H1, W1, H2, W2, 0.0f);
    stats_kernel<5><<<dim3(tx2, ty2, B), blk, 0, stream>>>(ref2, dist2, H2, W2, 0.0f, p2);

    // Scale 3
    down_kernel<3><<<dim3((W3 + 31) / 32, (H3 + 7) / 8, B), blk, 0, stream>>>(
        ref2, dist2, ref3, dist3, H2, W2, H3, W3, 0.0f);
    stats_kernel<3><<<dim3(tx3, ty3, B), blk, 0, stream>>>(ref3, dist3, H3, W3, 0.0f, p3);

    // Final: num/den per (b, scale)
    reduce_kernel<<<16, 256, 0, stream>>>(
        part, out,
        make_int4(0, B * n0, B * (n0 + n1), B * (n0 + n1 + n2)),
        make_int4(n0, n1, n2, n3));
}